// Round 2
// baseline (637.058 us; speedup 1.0000x reference)
//
#include <hip/hip_runtime.h>
#include <cstdint>
#include <cstddef>

typedef unsigned short u16;
typedef __bf16 bf16x8 __attribute__((ext_vector_type(8)));
typedef float f32x4 __attribute__((ext_vector_type(4)));

#define SLEN 2048
#define NHEADS 16
#define NGRP 4

__device__ inline float bf2f(u16 u) { return __uint_as_float(((unsigned)u) << 16); }
__device__ inline u16 f2bf(float f) {
    unsigned u = __float_as_uint(f);
    u += 0x7fffu + ((u >> 16) & 1u);
    return (u16)(u >> 16);
}

__device__ inline f32x4 mfma16(bf16x8 a, bf16x8 b, f32x4 c) {
    return __builtin_amdgcn_mfma_f32_16x16x32_bf16(a, b, c, 0, 0, 0);
}

__device__ inline void memfence_compiler() { __asm__ volatile("" ::: "memory"); }

// async global->LDS, 16B per lane; LDS dest = wave-uniform base + lane*16
__device__ inline void cp16(const u16* g, u16* l) {
    __builtin_amdgcn_global_load_lds(
        (__attribute__((address_space(1))) void*)(u16*)g,
        (__attribute__((address_space(3))) void*)l, 16, 0, 0);
}

// ---------------- fp32 -> bf16 convert, 4 elems/thread ----------------
__global__ __launch_bounds__(256) void convert_k(const float* __restrict__ in, u16* __restrict__ out,
                                                 long n) {
    long i = ((long)blockIdx.x * 256 + threadIdx.x) * 4;
    if (i >= n) return;
    float4 v = *(const float4*)(in + i);
    ushort4 o;
    o.x = f2bf(v.x); o.y = f2bf(v.y); o.z = f2bf(v.z); o.w = f2bf(v.w);
    *(ushort4*)(out + i) = o;
}

__global__ __launch_bounds__(128) void convert_small_k(const float* __restrict__ qw,
                                                       const float* __restrict__ kw,
                                                       u16* qwb, u16* kwb) {
    int t = threadIdx.x;
    qwb[t] = f2bf(qw[t]);
    kwb[t] = f2bf(kw[t]);
}

// ---------------- fp32 transpose + convert: in (R,C) fp32 -> out (C,R) bf16 ----------------
__global__ __launch_bounds__(256) void transpose_f32_k(const float* __restrict__ in,
                                                       u16* __restrict__ out, int R, int C) {
    __shared__ u16 tile[64][65];
    const int tid = threadIdx.x;
    const long r0 = (long)blockIdx.y * 64, c0 = (long)blockIdx.x * 64;
    for (int j = 0; j < 4; j++) {
        int c = j * 256 + tid;
        int lr = c >> 4, lc = (c & 15) * 4;
        float4 v = *(const float4*)&in[(r0 + lr) * (long)C + c0 + lc];
        tile[lr][lc + 0] = f2bf(v.x); tile[lr][lc + 1] = f2bf(v.y);
        tile[lr][lc + 2] = f2bf(v.z); tile[lr][lc + 3] = f2bf(v.w);
    }
    __syncthreads();
    for (int j = 0; j < 4; j++) {
        int c = j * 256 + tid;
        int orow = c >> 4, oc = (c & 15) * 4;
        ushort4 vv;
        vv.x = tile[oc + 0][orow]; vv.y = tile[oc + 1][orow];
        vv.z = tile[oc + 2][orow]; vv.w = tile[oc + 3][orow];
        *(ushort4*)&out[(c0 + orow) * (long)R + r0 + oc] = vv;
    }
}

// ---------------- bf16 transpose w/ input row stride: in (R,C)@inRS -> out (C,R) ----------------
__global__ __launch_bounds__(256) void transpose_bf_k(const u16* __restrict__ in, long inRS,
                                                      u16* __restrict__ out, int R, int C) {
    __shared__ u16 tile[64][65];
    const int tid = threadIdx.x;
    const long r0 = (long)blockIdx.y * 64, c0 = (long)blockIdx.x * 64;
    for (int j = 0; j < 4; j++) {
        int c = j * 256 + tid;
        int lr = c >> 4, lc = (c & 15) * 4;
        ushort4 vv = *(const ushort4*)&in[(r0 + lr) * inRS + c0 + lc];
        tile[lr][lc + 0] = vv.x; tile[lr][lc + 1] = vv.y;
        tile[lr][lc + 2] = vv.z; tile[lr][lc + 3] = vv.w;
    }
    __syncthreads();
    for (int j = 0; j < 4; j++) {
        int c = j * 256 + tid;
        int orow = c >> 4, oc = (c & 15) * 4;
        ushort4 vv;
        vv.x = tile[oc + 0][orow]; vv.y = tile[oc + 1][orow];
        vv.z = tile[oc + 2][orow]; vv.w = tile[oc + 3][orow];
        *(ushort4*)&out[(c0 + orow) * (long)R + r0 + oc] = vv;
    }
}

// ---------------- GEMM: C(M,N) = A(M,K) * Bt(N,K)^T, bf16 in, OutT out ----------------
template <typename OutT>
__global__ __launch_bounds__(256) void gemm_bt(const u16* __restrict__ A, const u16* __restrict__ Bt,
                                               OutT* __restrict__ C, int M, int N, int K) {
    __shared__ u16 As[128 * 32];
    __shared__ u16 Bs[128 * 32];
    const int tid = threadIdx.x;
    const int lane = tid & 63, wave = tid >> 6;
    const int l15 = lane & 15, quad = lane >> 4;
    const long m0 = (long)blockIdx.y * 128, n0 = (long)blockIdx.x * 128;
    const int wm = (wave >> 1) * 64, wn = (wave & 1) * 64;

    f32x4 acc[4][4];
    for (int i = 0; i < 4; i++)
        for (int j = 0; j < 4; j++) acc[i][j] = {0.f, 0.f, 0.f, 0.f};

    const u16* aG = A + (m0 + wave * 32 + (lane >> 2)) * (long)K + (lane & 3) * 8;
    const u16* bG = Bt + (n0 + wave * 32 + (lane >> 2)) * (long)K + (lane & 3) * 8;
    u16* aL = &As[wave * 1024];
    u16* bL = &Bs[wave * 1024];
    const long rowK16 = 16L * K;

    for (int kt = 0; kt < K; kt += 32) {
        cp16(aG + kt, aL);
        cp16(aG + kt + rowK16, aL + 512);
        cp16(bG + kt, bL);
        cp16(bG + kt + rowK16, bL + 512);
        __syncthreads();
        bf16x8 af[4], bfr[4];
        for (int mi = 0; mi < 4; mi++)
            af[mi] = *(const bf16x8*)&As[(wm + mi * 16 + l15) * 32 + quad * 8];
        for (int ni = 0; ni < 4; ni++)
            bfr[ni] = *(const bf16x8*)&Bs[(wn + ni * 16 + l15) * 32 + quad * 8];
        for (int mi = 0; mi < 4; mi++)
            for (int ni = 0; ni < 4; ni++)
                acc[mi][ni] = mfma16(af[mi], bfr[ni], acc[mi][ni]);
        __syncthreads();
    }
    for (int mi = 0; mi < 4; mi++)
        for (int r = 0; r < 4; r++) {
            long row = m0 + wm + mi * 16 + quad * 4 + r;
            OutT* crow = C + row * (long)N + n0 + wn + l15;
            for (int ni = 0; ni < 4; ni++) {
                float v = acc[mi][ni][r];
                if constexpr (sizeof(OutT) == 2) crow[ni * 16] = f2bf(v);
                else crow[ni * 16] = v;
            }
        }
}

// ---------------- RMSNorm + RoPE + scale (fp32 cos/sin), one wave per 128-elem row ----------------
__global__ __launch_bounds__(256) void normrope(u16* __restrict__ buf, long rowstride, int heads,
                                                const u16* __restrict__ w,
                                                const float* __restrict__ cosf, const float* __restrict__ sinf,
                                                float scale) {
    const int row = blockIdx.x * 4 + (threadIdx.x >> 6);
    const int lane = threadIdx.x & 63;
    u16* p = buf + (long)(row / heads) * rowstride + (row % heads) * 128;
    float x1 = bf2f(p[lane]);
    float x2 = bf2f(p[lane + 64]);
    float ss = x1 * x1 + x2 * x2;
    for (int off = 1; off < 64; off <<= 1) ss += __shfl_xor(ss, off);
    float inv = rsqrtf(ss * (1.f / 128.f) + 1e-6f);
    int s = (row / heads) % SLEN;
    float c1 = cosf[s * 128 + lane], c2 = cosf[s * 128 + 64 + lane];
    float s1 = sinf[s * 128 + lane], s2 = sinf[s * 128 + 64 + lane];
    float w1 = bf2f(w[lane]), w2 = bf2f(w[lane + 64]);
    float y1 = x1 * inv * w1, y2 = x2 * inv * w2;
    p[lane]      = f2bf((y1 * c1 - y2 * s1) * scale);
    p[lane + 64] = f2bf((y2 * c2 + y1 * s2) * scale);
}

// ---------------- causal flash attention v4: K-fragment register double-buffer ----------------
// qkv: (B*S, 3072) fused [q | k | v], q/k normed+roped (q scaled); vT: (512, B*S)
// ctx out: (B*S, 2048). Block = 4 waves x 32 q-rows = 128 rows of one (b,h).
// blockIdx%8 == (b,g) so each XCD's L2 holds exactly one K/vT working set (1 MB).
// S^T = K*Q^T via operand swap; row-stats in-lane; rowsum via ones-MFMA.
// v4: next tile's 16 K-fragment loads issued at body top into the alternate register
// set (ping-pong, 2-body unrolled while) so their L2 latency hides under this tile's
// QK+softmax+PV (~1500cy). VGPR headroom: 2 waves/SIMD => 256 VGPR budget, was 116.
__global__ __launch_bounds__(256, 2) void attn(const u16* __restrict__ qkv, const u16* __restrict__ vT,
                                               u16* __restrict__ ctx) {
    __shared__ u16 Ps[4][2][16][72];   // [wave][m][qrow16][t+pad]
    __shared__ float Al[4][2][16];     // alpha axis-swap
    const int tid = threadIdx.x;
    const int lane = tid & 63, wave = tid >> 6;
    const int l15 = lane & 15, quad = lane >> 4;
    const int bg = blockIdx.x & 7, b = bg >> 2, g = bg & 3;
    const int rest = blockIdx.x >> 3;
    const int h = g * 4 + (rest & 3);
    const int qt = 15 - (rest >> 2);        // longest first within each XCD
    const int wr = qt * 128 + wave * 32;    // this wave's first q-row

    union { bf16x8 v; u16 s[8]; } uo;
    for (int j = 0; j < 8; j++) uo.s[j] = 0x3F80;  // bf16 1.0
    const bf16x8 ones = uo.v;

    // Q fragments (B-operand layout; identical register layout to A)
    bf16x8 qa[2][4];
    for (int m = 0; m < 2; m++) {
        const u16* qp = qkv + (long)(b * SLEN + wr + m * 16 + l15) * 3072 + h * 128 + quad * 8;
        for (int kc = 0; kc < 4; kc++) qa[m][kc] = *(const bf16x8*)(qp + kc * 32);
    }
    float m_i[2] = {-__builtin_inff(), -__builtin_inff()};  // per q-row (m*16+l15)
    f32x4 l_acc[2];
    f32x4 o[2][8];
    for (int m = 0; m < 2; m++) l_acc[m] = {0.f, 0.f, 0.f, 0.f};
    for (int m = 0; m < 2; m++)
        for (int nf = 0; nf < 8; nf++) o[m][nf] = {0.f, 0.f, 0.f, 0.f};

    const u16* kbase = qkv + (long)b * SLEN * 3072 + 2048 + g * 128;
    const u16* vbase = vT + (long)g * 128 * 4096 + (long)b * SLEN;

    const int nit = (wr + 95) >> 6;    // number of 64-wide t-tiles

    bf16x8 kfA[4][4], kfB[4][4];
    // preload K tile 0 into A
    #pragma unroll
    for (int nf = 0; nf < 4; nf++) {
        const u16* kp = kbase + (long)(nf * 16 + l15) * 3072 + quad * 8;
        #pragma unroll
        for (int kc = 0; kc < 4; kc++) kfA[nf][kc] = *(const bf16x8*)(kp + kc * 32);
    }

    auto body = [&](int it, bf16x8 (&kfc)[4][4], bf16x8 (&kfn)[4][4]) {
        const int t0 = it * 64;
        // V first half early (latency hidden under QK + softmax)
        bf16x8 vf0[8];
        #pragma unroll
        for (int nf = 0; nf < 8; nf++)
            vf0[nf] = *(const bf16x8*)(vbase + (long)(nf * 16 + l15) * 4096 + t0 + quad * 8);
        // prefetch NEXT tile's K fragments into the alternate buffer
        if (it + 1 < nit) {
            const int t1 = t0 + 64;
            #pragma unroll
            for (int nf = 0; nf < 4; nf++) {
                const u16* kp = kbase + (long)(t1 + nf * 16 + l15) * 3072 + quad * 8;
                #pragma unroll
                for (int kc = 0; kc < 4; kc++) kfn[nf][kc] = *(const bf16x8*)(kp + kc * 32);
            }
        }

        // S^T = K * Q^T  (kfc loaded one tile ago -> ready, no exposed latency)
        f32x4 sc[2][4];
        for (int m = 0; m < 2; m++)
            for (int nf = 0; nf < 4; nf++) sc[m][nf] = {0.f, 0.f, 0.f, 0.f};
        #pragma unroll
        for (int kc = 0; kc < 4; kc++)
            #pragma unroll
            for (int nf = 0; nf < 4; nf++) {
                sc[0][nf] = mfma16(kfc[nf][kc], qa[0][kc], sc[0][nf]);
                sc[1][nf] = mfma16(kfc[nf][kc], qa[1][kc], sc[1][nf]);
            }
        // causal mask: t = t0+nf*16+quad*4+r (rows), qrow = wr+m*16+l15 (cols)
        if (t0 + 63 > wr) {
            #pragma unroll
            for (int m = 0; m < 2; m++) {
                int qrow = wr + m * 16 + l15;
                #pragma unroll
                for (int nf = 0; nf < 4; nf++)
                    #pragma unroll
                    for (int r = 0; r < 4; r++)
                        if (t0 + nf * 16 + quad * 4 + r > qrow) sc[m][nf][r] = -__builtin_inff();
            }
        }
        // row max: in-lane over nf,r then across quads (2 shuffles)
        float alpha[2];
        #pragma unroll
        for (int m = 0; m < 2; m++) {
            float mx = sc[m][0][0];
            #pragma unroll
            for (int nf = 0; nf < 4; nf++)
                #pragma unroll
                for (int r = 0; r < 4; r++) mx = fmaxf(mx, sc[m][nf][r]);
            mx = fmaxf(mx, __shfl_xor(mx, 16));
            mx = fmaxf(mx, __shfl_xor(mx, 32));
            float mn = fmaxf(m_i[m], mx);
            alpha[m] = __expf(m_i[m] - mn);
            m_i[m] = mn;
            Al[wave][m][l15] = alpha[m];
        }
        // exp + P store (P^T C-layout -> A-layout rows: 4 consecutive t per lane = b64)
        #pragma unroll
        for (int m = 0; m < 2; m++)
            #pragma unroll
            for (int nf = 0; nf < 4; nf++) {
                ushort4 pk;
                pk.x = f2bf(__expf(sc[m][nf][0] - m_i[m]));
                pk.y = f2bf(__expf(sc[m][nf][1] - m_i[m]));
                pk.z = f2bf(__expf(sc[m][nf][2] - m_i[m]));
                pk.w = f2bf(__expf(sc[m][nf][3] - m_i[m]));
                *(ushort4*)&Ps[wave][m][l15][nf * 16 + quad * 4] = pk;
            }
        memfence_compiler();
        // alpha on O-row axis (broadcast read), rescale o and l
        f32x4 al[2];
        al[0] = *(const f32x4*)&Al[wave][0][quad * 4];
        al[1] = *(const f32x4*)&Al[wave][1][quad * 4];
        #pragma unroll
        for (int m = 0; m < 2; m++) {
            #pragma unroll
            for (int nf = 0; nf < 8; nf++)
                #pragma unroll
                for (int r = 0; r < 4; r++) o[m][nf][r] *= al[m][r];
            #pragma unroll
            for (int r = 0; r < 4; r++) l_acc[m][r] *= al[m][r];
        }
        // PV, half 0 (issue half-1 V loads first so their latency overlaps)
        bf16x8 vf1[8];
        #pragma unroll
        for (int nf = 0; nf < 8; nf++)
            vf1[nf] = *(const bf16x8*)(vbase + (long)(nf * 16 + l15) * 4096 + t0 + 32 + quad * 8);
        {
            bf16x8 pa0 = *(const bf16x8*)&Ps[wave][0][l15][quad * 8];
            bf16x8 pa1 = *(const bf16x8*)&Ps[wave][1][l15][quad * 8];
            #pragma unroll
            for (int nf = 0; nf < 8; nf++) {
                o[0][nf] = mfma16(pa0, vf0[nf], o[0][nf]);
                o[1][nf] = mfma16(pa1, vf0[nf], o[1][nf]);
            }
            l_acc[0] = mfma16(pa0, ones, l_acc[0]);
            l_acc[1] = mfma16(pa1, ones, l_acc[1]);
        }
        // PV, half 1
        {
            bf16x8 pa0 = *(const bf16x8*)&Ps[wave][0][l15][32 + quad * 8];
            bf16x8 pa1 = *(const bf16x8*)&Ps[wave][1][l15][32 + quad * 8];
            #pragma unroll
            for (int nf = 0; nf < 8; nf++) {
                o[0][nf] = mfma16(pa0, vf1[nf], o[0][nf]);
                o[1][nf] = mfma16(pa1, vf1[nf], o[1][nf]);
            }
            l_acc[0] = mfma16(pa0, ones, l_acc[0]);
            l_acc[1] = mfma16(pa1, ones, l_acc[1]);
        }
        memfence_compiler();
    };

    int it = 0;
    while (true) {
        body(it, kfA, kfB);
        if (++it >= nit) break;
        body(it, kfB, kfA);
        if (++it >= nit) break;
    }

    #pragma unroll
    for (int m = 0; m < 2; m++)
        #pragma unroll
        for (int r = 0; r < 4; r++) {
            float inv = 1.f / l_acc[m][r];
            int srow = wr + m * 16 + quad * 4 + r;
            u16* cp = ctx + (long)(b * SLEN + srow) * 2048 + h * 128 + l15;
            #pragma unroll
            for (int nf = 0; nf < 8; nf++) cp[nf * 16] = f2bf(o[m][nf][r] * inv);
        }
}

extern "C" void kernel_launch(void* const* d_in, const int* in_sizes, int n_in,
                              void* d_out, int out_size, void* d_ws, size_t ws_size,
                              hipStream_t stream) {
    const float* x    = (const float*)d_in[0];
    // d_in[1] = mask (unused; causality from indices)
    const float* cosi = (const float*)d_in[2];
    const float* sini = (const float*)d_in[3];
    const float* Wq   = (const float*)d_in[4];
    const float* Wk   = (const float*)d_in[5];
    const float* Wv   = (const float*)d_in[6];
    const float* Wo   = (const float*)d_in[7];
    const float* qw   = (const float*)d_in[8];
    const float* kw   = (const float*)d_in[9];
    float* out = (float*)d_out;
    char* ws = (char*)d_ws;

    const size_t MB = 1 << 20;
    u16* qkvb  = (u16*)(ws);             // 4096x3072 bf16 = 24 MB  [0,24)
    u16* vTb   = (u16*)(ws + 24 * MB);   // 512x4096        = 4 MB  [24,28)
    u16* xbf   = (u16*)(ws + 28 * MB);   // 4096x2048       = 16 MB [28,44) dead after QKV GEMM
    u16* ctx   = (u16*)(ws + 28 * MB);   // reuses xbf region
    u16* wqkvT = (u16*)(ws + 44 * MB);   // 3072x2048       = 12 MB [44,56) dead after QKV GEMM
    u16* woT   = (u16*)(ws + 44 * MB);   // reuses wqkvT region (8 MB)
    u16* qwb   = (u16*)(ws + 56 * MB);
    u16* kwb   = (u16*)(ws + 56 * MB + 256);

    convert_k<<<8192, 256, 0, stream>>>(x, xbf, 8388608L);
    convert_small_k<<<1, 128, 0, stream>>>(qw, kw, qwb, kwb);

    // fused weight: rows 0..2047 = Wq^T, 2048..2559 = Wk^T, 2560..3071 = Wv^T
    transpose_f32_k<<<dim3(32, 32), 256, 0, stream>>>(Wq, wqkvT, 2048, 2048);
    transpose_f32_k<<<dim3(8, 32), 256, 0, stream>>>(Wk, wqkvT + 2048L * 2048, 2048, 512);
    transpose_f32_k<<<dim3(8, 32), 256, 0, stream>>>(Wv, wqkvT + 2560L * 2048, 2048, 512);

    gemm_bt<u16><<<dim3(24, 32), 256, 0, stream>>>(xbf, wqkvT, qkvb, 4096, 3072, 2048);

    // v columns (2560..3071) -> vT (512, 4096)
    transpose_bf_k<<<dim3(8, 64), 256, 0, stream>>>(qkvb + 2560, 3072L, vTb, 4096, 512);

    normrope<<<16384, 256, 0, stream>>>(qkvb, 3072L, NHEADS, qwb, cosi, sini, 0.08838834764831845f);
    normrope<<<4096, 256, 0, stream>>>(qkvb + 2048, 3072L, NGRP, kwb, cosi, sini, 1.0f);

    // Wo^T into the (now dead) wqkvT region
    transpose_f32_k<<<dim3(32, 32), 256, 0, stream>>>(Wo, woT, 2048, 2048);

    attn<<<dim3(512, 1, 1), 256, 0, stream>>>(qkvb, vTb, ctx);

    gemm_bt<float><<<dim3(16, 32), 256, 0, stream>>>(ctx, woT, out, 4096, 2048, 2048);
}

// Round 3
// 364.236 us; speedup vs baseline: 1.7490x; 1.7490x over previous
//
#include <hip/hip_runtime.h>
#include <cstdint>
#include <cstddef>

typedef unsigned short u16;
typedef __bf16 bf16x8 __attribute__((ext_vector_type(8)));
typedef float f32x4 __attribute__((ext_vector_type(4)));

#define SLEN 2048
#define NHEADS 16
#define NGRP 4

__device__ inline float bf2f(u16 u) { return __uint_as_float(((unsigned)u) << 16); }
__device__ inline u16 f2bf(float f) {
    unsigned u = __float_as_uint(f);
    u += 0x7fffu + ((u >> 16) & 1u);
    return (u16)(u >> 16);
}

__device__ inline f32x4 mfma16(bf16x8 a, bf16x8 b, f32x4 c) {
    return __builtin_amdgcn_mfma_f32_16x16x32_bf16(a, b, c, 0, 0, 0);
}

__device__ inline void memfence_compiler() { __asm__ volatile("" ::: "memory"); }

// async global->LDS, 16B per lane; LDS dest = wave-uniform base + lane*16
__device__ inline void cp16(const u16* g, u16* l) {
    __builtin_amdgcn_global_load_lds(
        (__attribute__((address_space(1))) void*)(u16*)g,
        (__attribute__((address_space(3))) void*)l, 16, 0, 0);
}

// ---------------- fp32 -> bf16 convert, 4 elems/thread ----------------
__global__ __launch_bounds__(256) void convert_k(const float* __restrict__ in, u16* __restrict__ out,
                                                 long n) {
    long i = ((long)blockIdx.x * 256 + threadIdx.x) * 4;
    if (i >= n) return;
    float4 v = *(const float4*)(in + i);
    ushort4 o;
    o.x = f2bf(v.x); o.y = f2bf(v.y); o.z = f2bf(v.z); o.w = f2bf(v.w);
    *(ushort4*)(out + i) = o;
}

__global__ __launch_bounds__(128) void convert_small_k(const float* __restrict__ qw,
                                                       const float* __restrict__ kw,
                                                       u16* qwb, u16* kwb) {
    int t = threadIdx.x;
    qwb[t] = f2bf(qw[t]);
    kwb[t] = f2bf(kw[t]);
}

// ---------------- fp32 transpose + convert: in (R,C) fp32 -> out (C,R) bf16 ----------------
__global__ __launch_bounds__(256) void transpose_f32_k(const float* __restrict__ in,
                                                       u16* __restrict__ out, int R, int C) {
    __shared__ u16 tile[64][65];
    const int tid = threadIdx.x;
    const long r0 = (long)blockIdx.y * 64, c0 = (long)blockIdx.x * 64;
    for (int j = 0; j < 4; j++) {
        int c = j * 256 + tid;
        int lr = c >> 4, lc = (c & 15) * 4;
        float4 v = *(const float4*)&in[(r0 + lr) * (long)C + c0 + lc];
        tile[lr][lc + 0] = f2bf(v.x); tile[lr][lc + 1] = f2bf(v.y);
        tile[lr][lc + 2] = f2bf(v.z); tile[lr][lc + 3] = f2bf(v.w);
    }
    __syncthreads();
    for (int j = 0; j < 4; j++) {
        int c = j * 256 + tid;
        int orow = c >> 4, oc = (c & 15) * 4;
        ushort4 vv;
        vv.x = tile[oc + 0][orow]; vv.y = tile[oc + 1][orow];
        vv.z = tile[oc + 2][orow]; vv.w = tile[oc + 3][orow];
        *(ushort4*)&out[(c0 + orow) * (long)R + r0 + oc] = vv;
    }
}

// ---------------- bf16 transpose w/ input row stride: in (R,C)@inRS -> out (C,R) ----------------
__global__ __launch_bounds__(256) void transpose_bf_k(const u16* __restrict__ in, long inRS,
                                                      u16* __restrict__ out, int R, int C) {
    __shared__ u16 tile[64][65];
    const int tid = threadIdx.x;
    const long r0 = (long)blockIdx.y * 64, c0 = (long)blockIdx.x * 64;
    for (int j = 0; j < 4; j++) {
        int c = j * 256 + tid;
        int lr = c >> 4, lc = (c & 15) * 4;
        ushort4 vv = *(const ushort4*)&in[(r0 + lr) * inRS + c0 + lc];
        tile[lr][lc + 0] = vv.x; tile[lr][lc + 1] = vv.y;
        tile[lr][lc + 2] = vv.z; tile[lr][lc + 3] = vv.w;
    }
    __syncthreads();
    for (int j = 0; j < 4; j++) {
        int c = j * 256 + tid;
        int orow = c >> 4, oc = (c & 15) * 4;
        ushort4 vv;
        vv.x = tile[oc + 0][orow]; vv.y = tile[oc + 1][orow];
        vv.z = tile[oc + 2][orow]; vv.w = tile[oc + 3][orow];
        *(ushort4*)&out[(c0 + orow) * (long)R + r0 + oc] = vv;
    }
}

// ---------------- GEMM: C(M,N) = A(M,K) * Bt(N,K)^T, bf16 in, OutT out ----------------
template <typename OutT>
__global__ __launch_bounds__(256) void gemm_bt(const u16* __restrict__ A, const u16* __restrict__ Bt,
                                               OutT* __restrict__ C, int M, int N, int K) {
    __shared__ u16 As[128 * 32];
    __shared__ u16 Bs[128 * 32];
    const int tid = threadIdx.x;
    const int lane = tid & 63, wave = tid >> 6;
    const int l15 = lane & 15, quad = lane >> 4;
    const long m0 = (long)blockIdx.y * 128, n0 = (long)blockIdx.x * 128;
    const int wm = (wave >> 1) * 64, wn = (wave & 1) * 64;

    f32x4 acc[4][4];
    for (int i = 0; i < 4; i++)
        for (int j = 0; j < 4; j++) acc[i][j] = {0.f, 0.f, 0.f, 0.f};

    const u16* aG = A + (m0 + wave * 32 + (lane >> 2)) * (long)K + (lane & 3) * 8;
    const u16* bG = Bt + (n0 + wave * 32 + (lane >> 2)) * (long)K + (lane & 3) * 8;
    u16* aL = &As[wave * 1024];
    u16* bL = &Bs[wave * 1024];
    const long rowK16 = 16L * K;

    for (int kt = 0; kt < K; kt += 32) {
        cp16(aG + kt, aL);
        cp16(aG + kt + rowK16, aL + 512);
        cp16(bG + kt, bL);
        cp16(bG + kt + rowK16, bL + 512);
        __syncthreads();
        bf16x8 af[4], bfr[4];
        for (int mi = 0; mi < 4; mi++)
            af[mi] = *(const bf16x8*)&As[(wm + mi * 16 + l15) * 32 + quad * 8];
        for (int ni = 0; ni < 4; ni++)
            bfr[ni] = *(const bf16x8*)&Bs[(wn + ni * 16 + l15) * 32 + quad * 8];
        for (int mi = 0; mi < 4; mi++)
            for (int ni = 0; ni < 4; ni++)
                acc[mi][ni] = mfma16(af[mi], bfr[ni], acc[mi][ni]);
        __syncthreads();
    }
    for (int mi = 0; mi < 4; mi++)
        for (int r = 0; r < 4; r++) {
            long row = m0 + wm + mi * 16 + quad * 4 + r;
            OutT* crow = C + row * (long)N + n0 + wn + l15;
            for (int ni = 0; ni < 4; ni++) {
                float v = acc[mi][ni][r];
                if constexpr (sizeof(OutT) == 2) crow[ni * 16] = f2bf(v);
                else crow[ni * 16] = v;
            }
        }
}

// ---------------- RMSNorm + RoPE + scale (fp32 cos/sin), one wave per 128-elem row ----------------
__global__ __launch_bounds__(256) void normrope(u16* __restrict__ buf, long rowstride, int heads,
                                                const u16* __restrict__ w,
                                                const float* __restrict__ cosf, const float* __restrict__ sinf,
                                                float scale) {
    const int row = blockIdx.x * 4 + (threadIdx.x >> 6);
    const int lane = threadIdx.x & 63;
    u16* p = buf + (long)(row / heads) * rowstride + (row % heads) * 128;
    float x1 = bf2f(p[lane]);
    float x2 = bf2f(p[lane + 64]);
    float ss = x1 * x1 + x2 * x2;
    for (int off = 1; off < 64; off <<= 1) ss += __shfl_xor(ss, off);
    float inv = rsqrtf(ss * (1.f / 128.f) + 1e-6f);
    int s = (row / heads) % SLEN;
    float c1 = cosf[s * 128 + lane], c2 = cosf[s * 128 + 64 + lane];
    float s1 = sinf[s * 128 + lane], s2 = sinf[s * 128 + 64 + lane];
    float w1 = bf2f(w[lane]), w2 = bf2f(w[lane + 64]);
    float y1 = x1 * inv * w1, y2 = x2 * inv * w2;
    p[lane]      = f2bf((y1 * c1 - y2 * s1) * scale);
    p[lane + 64] = f2bf((y2 * c2 + y1 * s2) * scale);
}

// ---------------- causal flash attention v5: block-shared LDS K/V staging ----------------
// qkv: (B*S, 3072) fused [q | k | v], q/k normed+roped (q scaled); vT: (512, B*S)
// ctx out: (B*S, 2048). Block = 4 waves x 32 q-rows = 128 rows of one (b,h).
// blockIdx%8 == (b,g) so each XCD's L2 holds exactly one K/vT working set (1 MB).
// v5: K-tile (64x128) and V-tile (128x64) staged in LDS ONCE per block per t-tile via
// global_load_lds (8 cp16/thread/iter) instead of 4 waves each re-loading identical
// fragments from L2 (was 32 VMEM instr x 16 lines each, latency-bound at 2 waves/SIMD).
// Rule-21 swizzle: LDS dest linear, global source chunk ^= (row&7), reads byte ^= ((row&7)<<4)
// -> conflict-free ds_read_b128. Single-buffered; exposed stage-wait covered by the
// co-resident second block (51.7 KB LDS -> 2 blocks/CU). Block-uniform loop nt=2qt+2;
// causally-done waves skip compute but keep staging+barriers.
// qt remap (idx<8 ? 15-idx : idx-8): co-resident pairs (idx, idx+8) have complementary
// work -> flat makespan.
__global__ __launch_bounds__(256, 2) void attn(const u16* __restrict__ qkv, const u16* __restrict__ vT,
                                               u16* __restrict__ ctx) {
    __shared__ u16 KB[64 * 128];       // K tile: row t (64) x col d (128), swizzled
    __shared__ u16 VB[128 * 64];       // V tile: row d (128) x col t (64), swizzled
    __shared__ u16 Ps[4][2][16][72];   // [wave][m][qrow16][t+pad]
    __shared__ float Al[4][2][16];     // alpha axis-swap
    const int tid = threadIdx.x;
    const int lane = tid & 63, wave = tid >> 6;
    const int l15 = lane & 15, quad = lane >> 4;
    const int bg = blockIdx.x & 7, b = bg >> 2, g = bg & 3;
    const int rest = blockIdx.x >> 3;
    const int h = g * 4 + (rest & 3);
    const int idx = rest >> 2;
    const int qt = (idx < 8) ? (15 - idx) : (idx - 8);   // complementary pairing
    const int wr = qt * 128 + wave * 32;    // this wave's first q-row

    union { bf16x8 v; u16 s[8]; } uo;
    for (int j = 0; j < 8; j++) uo.s[j] = 0x3F80;  // bf16 1.0
    const bf16x8 ones = uo.v;

    // Q fragments (B-operand layout; identical register layout to A)
    bf16x8 qa[2][4];
    for (int m = 0; m < 2; m++) {
        const u16* qp = qkv + (long)(b * SLEN + wr + m * 16 + l15) * 3072 + h * 128 + quad * 8;
        for (int kc = 0; kc < 4; kc++) qa[m][kc] = *(const bf16x8*)(qp + kc * 32);
    }
    float m_i[2] = {-__builtin_inff(), -__builtin_inff()};  // per q-row (m*16+l15)
    f32x4 l_acc[2];
    f32x4 o[2][8];
    for (int m = 0; m < 2; m++) l_acc[m] = {0.f, 0.f, 0.f, 0.f};
    for (int m = 0; m < 2; m++)
        for (int nf = 0; nf < 8; nf++) o[m][nf] = {0.f, 0.f, 0.f, 0.f};

    const u16* kqb = qkv + (long)b * SLEN * 3072 + 2048 + g * 128;   // K cols of (b,g)
    const u16* vgb = vT + (long)g * 128 * 4096 + (long)b * SLEN;     // vT rows of (b,g)
    const int xk = (l15 & 7) << 4;     // read-side swizzle XOR (byte)
    const int nt = 2 * qt + 2;         // block-uniform tile count

    for (int t = 0; t < nt; ++t) {
        const int t0 = t * 64;
        // ---- stage K (16 KB) + V (16 KB) into LDS; linear dest, pre-swizzled source ----
        #pragma unroll
        for (int i = 0; i < 4; ++i) {
            const int j = wave * 4 + i;
            {   // K: instr j covers rows j*4 .. j*4+3 (256 B/row, 16 chunks)
                const int row = j * 4 + (lane >> 4);
                const int cs = lane & 15;
                cp16(kqb + (long)(t0 + row) * 3072 + ((cs ^ (row & 7)) * 8), &KB[j * 512]);
            }
            {   // V: instr j covers rows j*8 .. j*8+7 (128 B/row, 8 chunks)
                const int row = j * 8 + (lane >> 3);
                const int cs = lane & 7;
                cp16(vgb + (long)row * 4096 + t0 + ((cs ^ (row & 7)) * 8), &VB[j * 512]);
            }
        }
        __syncthreads();   // drains each wave's vmcnt, then barrier: staging visible

        if (t0 <= wr + 31) {
            // K fragments from LDS (swizzled read)
            bf16x8 kf[4][4];
            #pragma unroll
            for (int nf = 0; nf < 4; nf++)
                #pragma unroll
                for (int kc = 0; kc < 4; kc++)
                    kf[nf][kc] = *(const bf16x8*)((const char*)KB +
                                  (nf * 16 + l15) * 256 + ((quad * 16 + kc * 64) ^ xk));

            // S^T = K * Q^T
            f32x4 sc[2][4];
            for (int m = 0; m < 2; m++)
                for (int nf = 0; nf < 4; nf++) sc[m][nf] = {0.f, 0.f, 0.f, 0.f};
            #pragma unroll
            for (int kc = 0; kc < 4; kc++)
                #pragma unroll
                for (int nf = 0; nf < 4; nf++) {
                    sc[0][nf] = mfma16(kf[nf][kc], qa[0][kc], sc[0][nf]);
                    sc[1][nf] = mfma16(kf[nf][kc], qa[1][kc], sc[1][nf]);
                }
            // causal mask: t = t0+nf*16+quad*4+r (rows), qrow = wr+m*16+l15 (cols)
            if (t0 + 63 > wr) {
                #pragma unroll
                for (int m = 0; m < 2; m++) {
                    int qrow = wr + m * 16 + l15;
                    #pragma unroll
                    for (int nf = 0; nf < 4; nf++)
                        #pragma unroll
                        for (int r = 0; r < 4; r++)
                            if (t0 + nf * 16 + quad * 4 + r > qrow) sc[m][nf][r] = -__builtin_inff();
                }
            }
            // row max: in-lane over nf,r then across quads (2 shuffles)
            float alpha[2];
            #pragma unroll
            for (int m = 0; m < 2; m++) {
                float mx = sc[m][0][0];
                #pragma unroll
                for (int nf = 0; nf < 4; nf++)
                    #pragma unroll
                    for (int r = 0; r < 4; r++) mx = fmaxf(mx, sc[m][nf][r]);
                mx = fmaxf(mx, __shfl_xor(mx, 16));
                mx = fmaxf(mx, __shfl_xor(mx, 32));
                float mn = fmaxf(m_i[m], mx);
                alpha[m] = __expf(m_i[m] - mn);
                m_i[m] = mn;
                Al[wave][m][l15] = alpha[m];
            }
            // exp + P store (P^T C-layout -> A-layout rows: 4 consecutive t per lane = b64)
            #pragma unroll
            for (int m = 0; m < 2; m++)
                #pragma unroll
                for (int nf = 0; nf < 4; nf++) {
                    ushort4 pk;
                    pk.x = f2bf(__expf(sc[m][nf][0] - m_i[m]));
                    pk.y = f2bf(__expf(sc[m][nf][1] - m_i[m]));
                    pk.z = f2bf(__expf(sc[m][nf][2] - m_i[m]));
                    pk.w = f2bf(__expf(sc[m][nf][3] - m_i[m]));
                    *(ushort4*)&Ps[wave][m][l15][nf * 16 + quad * 4] = pk;
                }
            memfence_compiler();
            // alpha on O-row axis (broadcast read), rescale o and l
            f32x4 al[2];
            al[0] = *(const f32x4*)&Al[wave][0][quad * 4];
            al[1] = *(const f32x4*)&Al[wave][1][quad * 4];
            #pragma unroll
            for (int m = 0; m < 2; m++) {
                #pragma unroll
                for (int nf = 0; nf < 8; nf++)
                    #pragma unroll
                    for (int r = 0; r < 4; r++) o[m][nf][r] *= al[m][r];
                #pragma unroll
                for (int r = 0; r < 4; r++) l_acc[m][r] *= al[m][r];
            }
            // PV, half 0 (V fragments from LDS, swizzled read)
            {
                bf16x8 vf[8];
                #pragma unroll
                for (int nf = 0; nf < 8; nf++)
                    vf[nf] = *(const bf16x8*)((const char*)VB +
                              (nf * 16 + l15) * 128 + ((quad * 16) ^ xk));
                bf16x8 pa0 = *(const bf16x8*)&Ps[wave][0][l15][quad * 8];
                bf16x8 pa1 = *(const bf16x8*)&Ps[wave][1][l15][quad * 8];
                #pragma unroll
                for (int nf = 0; nf < 8; nf++) {
                    o[0][nf] = mfma16(pa0, vf[nf], o[0][nf]);
                    o[1][nf] = mfma16(pa1, vf[nf], o[1][nf]);
                }
                l_acc[0] = mfma16(pa0, ones, l_acc[0]);
                l_acc[1] = mfma16(pa1, ones, l_acc[1]);
            }
            // PV, half 1
            {
                bf16x8 vf[8];
                #pragma unroll
                for (int nf = 0; nf < 8; nf++)
                    vf[nf] = *(const bf16x8*)((const char*)VB +
                              (nf * 16 + l15) * 128 + ((64 + quad * 16) ^ xk));
                bf16x8 pa0 = *(const bf16x8*)&Ps[wave][0][l15][32 + quad * 8];
                bf16x8 pa1 = *(const bf16x8*)&Ps[wave][1][l15][32 + quad * 8];
                #pragma unroll
                for (int nf = 0; nf < 8; nf++) {
                    o[0][nf] = mfma16(pa0, vf[nf], o[0][nf]);
                    o[1][nf] = mfma16(pa1, vf[nf], o[1][nf]);
                }
                l_acc[0] = mfma16(pa0, ones, l_acc[0]);
                l_acc[1] = mfma16(pa1, ones, l_acc[1]);
            }
            memfence_compiler();
        }
        __syncthreads();   // all reads of KB/VB done before next tile's overwrite
    }

    #pragma unroll
    for (int m = 0; m < 2; m++)
        #pragma unroll
        for (int r = 0; r < 4; r++) {
            float inv = 1.f / l_acc[m][r];
            int srow = wr + m * 16 + quad * 4 + r;
            u16* cp = ctx + (long)(b * SLEN + srow) * 2048 + h * 128 + l15;
            #pragma unroll
            for (int nf = 0; nf < 8; nf++) cp[nf * 16] = f2bf(o[m][nf][r] * inv);
        }
}

extern "C" void kernel_launch(void* const* d_in, const int* in_sizes, int n_in,
                              void* d_out, int out_size, void* d_ws, size_t ws_size,
                              hipStream_t stream) {
    const float* x    = (const float*)d_in[0];
    // d_in[1] = mask (unused; causality from indices)
    const float* cosi = (const float*)d_in[2];
    const float* sini = (const float*)d_in[3];
    const float* Wq   = (const float*)d_in[4];
    const float* Wk   = (const float*)d_in[5];
    const float* Wv   = (const float*)d_in[6];
    const float* Wo   = (const float*)d_in[7];
    const float* qw   = (const float*)d_in[8];
    const float* kw   = (const float*)d_in[9];
    float* out = (float*)d_out;
    char* ws = (char*)d_ws;

    const size_t MB = 1 << 20;
    u16* qkvb  = (u16*)(ws);             // 4096x3072 bf16 = 24 MB  [0,24)
    u16* vTb   = (u16*)(ws + 24 * MB);   // 512x4096        = 4 MB  [24,28)
    u16* xbf   = (u16*)(ws + 28 * MB);   // 4096x2048       = 16 MB [28,44) dead after QKV GEMM
    u16* ctx   = (u16*)(ws + 28 * MB);   // reuses xbf region
    u16* wqkvT = (u16*)(ws + 44 * MB);   // 3072x2048       = 12 MB [44,56) dead after QKV GEMM
    u16* woT   = (u16*)(ws + 44 * MB);   // reuses wqkvT region (8 MB)
    u16* qwb   = (u16*)(ws + 56 * MB);
    u16* kwb   = (u16*)(ws + 56 * MB + 256);

    convert_k<<<8192, 256, 0, stream>>>(x, xbf, 8388608L);
    convert_small_k<<<1, 128, 0, stream>>>(qw, kw, qwb, kwb);

    // fused weight: rows 0..2047 = Wq^T, 2048..2559 = Wk^T, 2560..3071 = Wv^T
    transpose_f32_k<<<dim3(32, 32), 256, 0, stream>>>(Wq, wqkvT, 2048, 2048);
    transpose_f32_k<<<dim3(8, 32), 256, 0, stream>>>(Wk, wqkvT + 2048L * 2048, 2048, 512);
    transpose_f32_k<<<dim3(8, 32), 256, 0, stream>>>(Wv, wqkvT + 2560L * 2048, 2048, 512);

    gemm_bt<u16><<<dim3(24, 32), 256, 0, stream>>>(xbf, wqkvT, qkvb, 4096, 3072, 2048);

    // v columns (2560..3071) -> vT (512, 4096)
    transpose_bf_k<<<dim3(8, 64), 256, 0, stream>>>(qkvb + 2560, 3072L, vTb, 4096, 512);

    normrope<<<16384, 256, 0, stream>>>(qkvb, 3072L, NHEADS, qwb, cosi, sini, 0.08838834764831845f);
    normrope<<<4096, 256, 0, stream>>>(qkvb + 2048, 3072L, NGRP, kwb, cosi, sini, 1.0f);

    // Wo^T into the (now dead) wqkvT region
    transpose_f32_k<<<dim3(32, 32), 256, 0, stream>>>(Wo, woT, 2048, 2048);

    attn<<<dim3(512, 1, 1), 256, 0, stream>>>(qkvb, vTb, ctx);

    gemm_bt<float><<<dim3(16, 32), 256, 0, stream>>>(ctx, woT, out, 4096, 2048, 2048);
}

// Round 4
// 354.438 us; speedup vs baseline: 1.7974x; 1.0276x over previous
//
#include <hip/hip_runtime.h>
#include <cstdint>
#include <cstddef>

typedef unsigned short u16;
typedef __bf16 bf16x8 __attribute__((ext_vector_type(8)));
typedef float f32x4 __attribute__((ext_vector_type(4)));

#define SLEN 2048
#define NHEADS 16
#define NGRP 4

__device__ inline float bf2f(u16 u) { return __uint_as_float(((unsigned)u) << 16); }
__device__ inline u16 f2bf(float f) {
    unsigned u = __float_as_uint(f);
    u += 0x7fffu + ((u >> 16) & 1u);
    return (u16)(u >> 16);
}

__device__ inline f32x4 mfma16(bf16x8 a, bf16x8 b, f32x4 c) {
    return __builtin_amdgcn_mfma_f32_16x16x32_bf16(a, b, c, 0, 0, 0);
}

__device__ inline void memfence_compiler() { __asm__ volatile("" ::: "memory"); }

// async global->LDS, 16B per lane; LDS dest = wave-uniform base + lane*16
__device__ inline void cp16(const u16* g, u16* l) {
    __builtin_amdgcn_global_load_lds(
        (__attribute__((address_space(1))) void*)(u16*)g,
        (__attribute__((address_space(3))) void*)l, 16, 0, 0);
}

// ---------------- fp32 -> bf16 convert, 4 elems/thread ----------------
__global__ __launch_bounds__(256) void convert_k(const float* __restrict__ in, u16* __restrict__ out,
                                                 long n) {
    long i = ((long)blockIdx.x * 256 + threadIdx.x) * 4;
    if (i >= n) return;
    float4 v = *(const float4*)(in + i);
    ushort4 o;
    o.x = f2bf(v.x); o.y = f2bf(v.y); o.z = f2bf(v.z); o.w = f2bf(v.w);
    *(ushort4*)(out + i) = o;
}

__global__ __launch_bounds__(128) void convert_small_k(const float* __restrict__ qw,
                                                       const float* __restrict__ kw,
                                                       u16* qwb, u16* kwb) {
    int t = threadIdx.x;
    qwb[t] = f2bf(qw[t]);
    kwb[t] = f2bf(kw[t]);
}

// ---------------- fp32 transpose + convert: in (R,C) fp32 -> out (C,R) bf16 ----------------
__global__ __launch_bounds__(256) void transpose_f32_k(const float* __restrict__ in,
                                                       u16* __restrict__ out, int R, int C) {
    __shared__ u16 tile[64][65];
    const int tid = threadIdx.x;
    const long r0 = (long)blockIdx.y * 64, c0 = (long)blockIdx.x * 64;
    for (int j = 0; j < 4; j++) {
        int c = j * 256 + tid;
        int lr = c >> 4, lc = (c & 15) * 4;
        float4 v = *(const float4*)&in[(r0 + lr) * (long)C + c0 + lc];
        tile[lr][lc + 0] = f2bf(v.x); tile[lr][lc + 1] = f2bf(v.y);
        tile[lr][lc + 2] = f2bf(v.z); tile[lr][lc + 3] = f2bf(v.w);
    }
    __syncthreads();
    for (int j = 0; j < 4; j++) {
        int c = j * 256 + tid;
        int orow = c >> 4, oc = (c & 15) * 4;
        ushort4 vv;
        vv.x = tile[oc + 0][orow]; vv.y = tile[oc + 1][orow];
        vv.z = tile[oc + 2][orow]; vv.w = tile[oc + 3][orow];
        *(ushort4*)&out[(c0 + orow) * (long)R + r0 + oc] = vv;
    }
}

// ---------------- bf16 transpose w/ input row stride: in (R,C)@inRS -> out (C,R) ----------------
__global__ __launch_bounds__(256) void transpose_bf_k(const u16* __restrict__ in, long inRS,
                                                      u16* __restrict__ out, int R, int C) {
    __shared__ u16 tile[64][65];
    const int tid = threadIdx.x;
    const long r0 = (long)blockIdx.y * 64, c0 = (long)blockIdx.x * 64;
    for (int j = 0; j < 4; j++) {
        int c = j * 256 + tid;
        int lr = c >> 4, lc = (c & 15) * 4;
        ushort4 vv = *(const ushort4*)&in[(r0 + lr) * inRS + c0 + lc];
        tile[lr][lc + 0] = vv.x; tile[lr][lc + 1] = vv.y;
        tile[lr][lc + 2] = vv.z; tile[lr][lc + 3] = vv.w;
    }
    __syncthreads();
    for (int j = 0; j < 4; j++) {
        int c = j * 256 + tid;
        int orow = c >> 4, oc = (c & 15) * 4;
        ushort4 vv;
        vv.x = tile[oc + 0][orow]; vv.y = tile[oc + 1][orow];
        vv.z = tile[oc + 2][orow]; vv.w = tile[oc + 3][orow];
        *(ushort4*)&out[(c0 + orow) * (long)R + r0 + oc] = vv;
    }
}

// ---------------- GEMM v2: 256x256 tile, BK=64, counted-vmcnt deep pipeline ----------------
// C(M,N) = A(M,K) * Bt(N,K)^T, bf16 in, OutT out. 512 threads = 8 waves (2M x 4N),
// per-wave C = 128x64 (acc 8x4 f32x4 = 128 VGPR). LDS 128 KiB dynamic:
// [As0|As1|Bs0|Bs1], each 256x64 bf16 (32 KB), double-buffered by K-tile parity.
// Pipeline: while computing tile t from buf[t&1], tile t+1's 16 global_load_lds fly
// into buf[~t&1] (issued at iter top, AFTER the end-barrier retiring that buffer's
// readers). Wait = counted vmcnt(8) (own tile-t loads landed, t+1's stay in flight),
// then raw s_barrier (no compiler vmcnt(0) drain as with __syncthreads). 2 barriers/K-tile.
// T2 swizzle both-sides (rule 21): linear LDS dest; SOURCE chunk c^(r&7); READ chunk
// (ks*4+quad)^(row&7). 16 lanes -> 8 distinct 4-bank groups x2 = conflict-free b128.
template <typename OutT>
__global__ __launch_bounds__(512, 2) void gemm256(const u16* __restrict__ A, const u16* __restrict__ Bt,
                                                  OutT* __restrict__ C, int N, int K) {
    extern __shared__ u16 smem[];   // As0,As1,Bs0,Bs1 : 4 x 16384 u16
    const int tid = threadIdx.x;
    const int lane = tid & 63, wave = tid >> 6;
    const int l15 = lane & 15, quad = lane >> 4;
    const int wm = (wave >> 2) * 128, wn = (wave & 3) * 64;
    const long m0 = (long)blockIdx.y * 256, n0 = (long)blockIdx.x * 256;

    f32x4 acc[8][4];
    #pragma unroll
    for (int i = 0; i < 8; i++)
        #pragma unroll
        for (int j = 0; j < 4; j++) acc[i][j] = {0.f, 0.f, 0.f, 0.f};

    const int sn = wave * 64 + lane;          // 0..511 (chunk id within 512-chunk group)
    const u16* aBase = A + m0 * (long)K;
    const u16* bBase = Bt + n0 * (long)K;

    auto stage = [&](int kt, int p) {
        // per matrix: 2048 16B-chunks (256 rows x 8), 4 cp16/thread
        u16* al = smem + p * 16384 + wave * 512;            // wave-uniform base
        u16* bl = smem + 32768 + p * 16384 + wave * 512;
        #pragma unroll
        for (int j = 0; j < 4; j++) {
            int n = j * 512 + sn;
            int r = n >> 3;
            int c = (n & 7) ^ (r & 7);                      // inverse-swizzled source chunk
            cp16(aBase + (long)r * K + kt + c * 8, al + j * 4096);
            cp16(bBase + (long)r * K + kt + c * 8, bl + j * 4096);
        }
    };

    stage(0, 0);                               // tile 0 -> buf0 (8 loads in flight)
    const int nkt = K >> 6;

    for (int t = 0; t < nkt; ++t) {
        const int cur = t & 1;
        if (t + 1 < nkt) {
            stage((t + 1) << 6, cur ^ 1);      // tile t+1 -> other buf (+16 loads)
            asm volatile("s_waitcnt vmcnt(8)" ::: "memory");   // tile t's 16 landed
        } else {
            asm volatile("s_waitcnt vmcnt(0)" ::: "memory");
        }
        __builtin_amdgcn_s_barrier();          // all waves' tile-t loads visible

        const u16* asb = smem + cur * 16384;
        const u16* bsb = smem + 32768 + cur * 16384;

        bf16x8 bfr[4][2];
        #pragma unroll
        for (int ni = 0; ni < 4; ni++) {
            const int row = wn + ni * 16 + l15;
            #pragma unroll
            for (int ks = 0; ks < 2; ks++)
                bfr[ni][ks] = *(const bf16x8*)&bsb[row * 64 + (((ks << 2) + quad) ^ (row & 7)) * 8];
        }
        #pragma unroll
        for (int mq = 0; mq < 2; mq++) {
            bf16x8 af[4][2];
            #pragma unroll
            for (int mi = 0; mi < 4; mi++) {
                const int row = wm + mq * 64 + mi * 16 + l15;
                #pragma unroll
                for (int ks = 0; ks < 2; ks++)
                    af[mi][ks] = *(const bf16x8*)&asb[row * 64 + (((ks << 2) + quad) ^ (row & 7)) * 8];
            }
            #pragma unroll
            for (int mi = 0; mi < 4; mi++)
                #pragma unroll
                for (int ni = 0; ni < 4; ni++) {
                    f32x4 v = acc[mq * 4 + mi][ni];
                    v = mfma16(af[mi][0], bfr[ni][0], v);
                    v = mfma16(af[mi][1], bfr[ni][1], v);
                    acc[mq * 4 + mi][ni] = v;
                }
        }
        __builtin_amdgcn_s_barrier();          // buf[cur] readers retired -> writable next iter
    }

    #pragma unroll
    for (int mi = 0; mi < 8; mi++)
        #pragma unroll
        for (int r = 0; r < 4; r++) {
            long row = m0 + wm + mi * 16 + quad * 4 + r;
            OutT* crow = C + row * (long)N + n0 + wn + l15;
            #pragma unroll
            for (int ni = 0; ni < 4; ni++) {
                float v = acc[mi][ni][r];
                if constexpr (sizeof(OutT) == 2) crow[ni * 16] = f2bf(v);
                else crow[ni * 16] = v;
            }
        }
}

// ---------------- RMSNorm + RoPE + scale (fp32 cos/sin), one wave per 128-elem row ----------------
__global__ __launch_bounds__(256) void normrope(u16* __restrict__ buf, long rowstride, int heads,
                                                const u16* __restrict__ w,
                                                const float* __restrict__ cosf, const float* __restrict__ sinf,
                                                float scale) {
    const int row = blockIdx.x * 4 + (threadIdx.x >> 6);
    const int lane = threadIdx.x & 63;
    u16* p = buf + (long)(row / heads) * rowstride + (row % heads) * 128;
    float x1 = bf2f(p[lane]);
    float x2 = bf2f(p[lane + 64]);
    float ss = x1 * x1 + x2 * x2;
    for (int off = 1; off < 64; off <<= 1) ss += __shfl_xor(ss, off);
    float inv = rsqrtf(ss * (1.f / 128.f) + 1e-6f);
    int s = (row / heads) % SLEN;
    float c1 = cosf[s * 128 + lane], c2 = cosf[s * 128 + 64 + lane];
    float s1 = sinf[s * 128 + lane], s2 = sinf[s * 128 + 64 + lane];
    float w1 = bf2f(w[lane]), w2 = bf2f(w[lane + 64]);
    float y1 = x1 * inv * w1, y2 = x2 * inv * w2;
    p[lane]      = f2bf((y1 * c1 - y2 * s1) * scale);
    p[lane + 64] = f2bf((y2 * c2 + y1 * s2) * scale);
}

// ---------------- causal flash attention v5: block-shared LDS K/V staging ----------------
// (unchanged from round 3: 80.5 us, MfmaUtil 17.6%)
__global__ __launch_bounds__(256, 2) void attn(const u16* __restrict__ qkv, const u16* __restrict__ vT,
                                               u16* __restrict__ ctx) {
    __shared__ u16 KB[64 * 128];       // K tile: row t (64) x col d (128), swizzled
    __shared__ u16 VB[128 * 64];       // V tile: row d (128) x col t (64), swizzled
    __shared__ u16 Ps[4][2][16][72];   // [wave][m][qrow16][t+pad]
    __shared__ float Al[4][2][16];     // alpha axis-swap
    const int tid = threadIdx.x;
    const int lane = tid & 63, wave = tid >> 6;
    const int l15 = lane & 15, quad = lane >> 4;
    const int bg = blockIdx.x & 7, b = bg >> 2, g = bg & 3;
    const int rest = blockIdx.x >> 3;
    const int h = g * 4 + (rest & 3);
    const int idx = rest >> 2;
    const int qt = (idx < 8) ? (15 - idx) : (idx - 8);   // complementary pairing
    const int wr = qt * 128 + wave * 32;    // this wave's first q-row

    union { bf16x8 v; u16 s[8]; } uo;
    for (int j = 0; j < 8; j++) uo.s[j] = 0x3F80;  // bf16 1.0
    const bf16x8 ones = uo.v;

    // Q fragments (B-operand layout; identical register layout to A)
    bf16x8 qa[2][4];
    for (int m = 0; m < 2; m++) {
        const u16* qp = qkv + (long)(b * SLEN + wr + m * 16 + l15) * 3072 + h * 128 + quad * 8;
        for (int kc = 0; kc < 4; kc++) qa[m][kc] = *(const bf16x8*)(qp + kc * 32);
    }
    float m_i[2] = {-__builtin_inff(), -__builtin_inff()};  // per q-row (m*16+l15)
    f32x4 l_acc[2];
    f32x4 o[2][8];
    for (int m = 0; m < 2; m++) l_acc[m] = {0.f, 0.f, 0.f, 0.f};
    for (int m = 0; m < 2; m++)
        for (int nf = 0; nf < 8; nf++) o[m][nf] = {0.f, 0.f, 0.f, 0.f};

    const u16* kqb = qkv + (long)b * SLEN * 3072 + 2048 + g * 128;   // K cols of (b,g)
    const u16* vgb = vT + (long)g * 128 * 4096 + (long)b * SLEN;     // vT rows of (b,g)
    const int xk = (l15 & 7) << 4;     // read-side swizzle XOR (byte)
    const int nt = 2 * qt + 2;         // block-uniform tile count

    for (int t = 0; t < nt; ++t) {
        const int t0 = t * 64;
        // ---- stage K (16 KB) + V (16 KB) into LDS; linear dest, pre-swizzled source ----
        #pragma unroll
        for (int i = 0; i < 4; ++i) {
            const int j = wave * 4 + i;
            {   // K: instr j covers rows j*4 .. j*4+3 (256 B/row, 16 chunks)
                const int row = j * 4 + (lane >> 4);
                const int cs = lane & 15;
                cp16(kqb + (long)(t0 + row) * 3072 + ((cs ^ (row & 7)) * 8), &KB[j * 512]);
            }
            {   // V: instr j covers rows j*8 .. j*8+7 (128 B/row, 8 chunks)
                const int row = j * 8 + (lane >> 3);
                const int cs = lane & 7;
                cp16(vgb + (long)row * 4096 + t0 + ((cs ^ (row & 7)) * 8), &VB[j * 512]);
            }
        }
        __syncthreads();   // drains each wave's vmcnt, then barrier: staging visible

        if (t0 <= wr + 31) {
            // K fragments from LDS (swizzled read)
            bf16x8 kf[4][4];
            #pragma unroll
            for (int nf = 0; nf < 4; nf++)
                #pragma unroll
                for (int kc = 0; kc < 4; kc++)
                    kf[nf][kc] = *(const bf16x8*)((const char*)KB +
                                  (nf * 16 + l15) * 256 + ((quad * 16 + kc * 64) ^ xk));

            // S^T = K * Q^T
            f32x4 sc[2][4];
            for (int m = 0; m < 2; m++)
                for (int nf = 0; nf < 4; nf++) sc[m][nf] = {0.f, 0.f, 0.f, 0.f};
            #pragma unroll
            for (int kc = 0; kc < 4; kc++)
                #pragma unroll
                for (int nf = 0; nf < 4; nf++) {
                    sc[0][nf] = mfma16(kf[nf][kc], qa[0][kc], sc[0][nf]);
                    sc[1][nf] = mfma16(kf[nf][kc], qa[1][kc], sc[1][nf]);
                }
            // causal mask: t = t0+nf*16+quad*4+r (rows), qrow = wr+m*16+l15 (cols)
            if (t0 + 63 > wr) {
                #pragma unroll
                for (int m = 0; m < 2; m++) {
                    int qrow = wr + m * 16 + l15;
                    #pragma unroll
                    for (int nf = 0; nf < 4; nf++)
                        #pragma unroll
                        for (int r = 0; r < 4; r++)
                            if (t0 + nf * 16 + quad * 4 + r > qrow) sc[m][nf][r] = -__builtin_inff();
                }
            }
            // row max: in-lane over nf,r then across quads (2 shuffles)
            float alpha[2];
            #pragma unroll
            for (int m = 0; m < 2; m++) {
                float mx = sc[m][0][0];
                #pragma unroll
                for (int nf = 0; nf < 4; nf++)
                    #pragma unroll
                    for (int r = 0; r < 4; r++) mx = fmaxf(mx, sc[m][nf][r]);
                mx = fmaxf(mx, __shfl_xor(mx, 16));
                mx = fmaxf(mx, __shfl_xor(mx, 32));
                float mn = fmaxf(m_i[m], mx);
                alpha[m] = __expf(m_i[m] - mn);
                m_i[m] = mn;
                Al[wave][m][l15] = alpha[m];
            }
            // exp + P store (P^T C-layout -> A-layout rows: 4 consecutive t per lane = b64)
            #pragma unroll
            for (int m = 0; m < 2; m++)
                #pragma unroll
                for (int nf = 0; nf < 4; nf++) {
                    ushort4 pk;
                    pk.x = f2bf(__expf(sc[m][nf][0] - m_i[m]));
                    pk.y = f2bf(__expf(sc[m][nf][1] - m_i[m]));
                    pk.z = f2bf(__expf(sc[m][nf][2] - m_i[m]));
                    pk.w = f2bf(__expf(sc[m][nf][3] - m_i[m]));
                    *(ushort4*)&Ps[wave][m][l15][nf * 16 + quad * 4] = pk;
                }
        memfence_compiler();
            // alpha on O-row axis (broadcast read), rescale o and l
            f32x4 al[2];
            al[0] = *(const f32x4*)&Al[wave][0][quad * 4];
            al[1] = *(const f32x4*)&Al[wave][1][quad * 4];
            #pragma unroll
            for (int m = 0; m < 2; m++) {
                #pragma unroll
                for (int nf = 0; nf < 8; nf++)
                    #pragma unroll
                    for (int r = 0; r < 4; r++) o[m][nf][r] *= al[m][r];
                #pragma unroll
                for (int r = 0; r < 4; r++) l_acc[m][r] *= al[m][r];
            }
            // PV, half 0 (V fragments from LDS, swizzled read)
            {
                bf16x8 vf[8];
                #pragma unroll
                for (int nf = 0; nf < 8; nf++)
                    vf[nf] = *(const bf16x8*)((const char*)VB +
                              (nf * 16 + l15) * 128 + ((quad * 16) ^ xk));
                bf16x8 pa0 = *(const bf16x8*)&Ps[wave][0][l15][quad * 8];
                bf16x8 pa1 = *(const bf16x8*)&Ps[wave][1][l15][quad * 8];
                #pragma unroll
                for (int nf = 0; nf < 8; nf++) {
                    o[0][nf] = mfma16(pa0, vf[nf], o[0][nf]);
                    o[1][nf] = mfma16(pa1, vf[nf], o[1][nf]);
                }
                l_acc[0] = mfma16(pa0, ones, l_acc[0]);
                l_acc[1] = mfma16(pa1, ones, l_acc[1]);
            }
            // PV, half 1
            {
                bf16x8 vf[8];
                #pragma unroll
                for (int nf = 0; nf < 8; nf++)
                    vf[nf] = *(const bf16x8*)((const char*)VB +
                              (nf * 16 + l15) * 128 + ((64 + quad * 16) ^ xk));
                bf16x8 pa0 = *(const bf16x8*)&Ps[wave][0][l15][32 + quad * 8];
                bf16x8 pa1 = *(const bf16x8*)&Ps[wave][1][l15][32 + quad * 8];
                #pragma unroll
                for (int nf = 0; nf < 8; nf++) {
                    o[0][nf] = mfma16(pa0, vf[nf], o[0][nf]);
                    o[1][nf] = mfma16(pa1, vf[nf], o[1][nf]);
                }
                l_acc[0] = mfma16(pa0, ones, l_acc[0]);
                l_acc[1] = mfma16(pa1, ones, l_acc[1]);
            }
            memfence_compiler();
        }
        __syncthreads();   // all reads of KB/VB done before next tile's overwrite
    }

    #pragma unroll
    for (int m = 0; m < 2; m++)
        #pragma unroll
        for (int r = 0; r < 4; r++) {
            float inv = 1.f / l_acc[m][r];
            int srow = wr + m * 16 + quad * 4 + r;
            u16* cp = ctx + (long)(b * SLEN + srow) * 2048 + h * 128 + l15;
            #pragma unroll
            for (int nf = 0; nf < 8; nf++) cp[nf * 16] = f2bf(o[m][nf][r] * inv);
        }
}

extern "C" void kernel_launch(void* const* d_in, const int* in_sizes, int n_in,
                              void* d_out, int out_size, void* d_ws, size_t ws_size,
                              hipStream_t stream) {
    const float* x    = (const float*)d_in[0];
    // d_in[1] = mask (unused; causality from indices)
    const float* cosi = (const float*)d_in[2];
    const float* sini = (const float*)d_in[3];
    const float* Wq   = (const float*)d_in[4];
    const float* Wk   = (const float*)d_in[5];
    const float* Wv   = (const float*)d_in[6];
    const float* Wo   = (const float*)d_in[7];
    const float* qw   = (const float*)d_in[8];
    const float* kw   = (const float*)d_in[9];
    float* out = (float*)d_out;
    char* ws = (char*)d_ws;

    const size_t MB = 1 << 20;
    u16* qkvb  = (u16*)(ws);             // 4096x3072 bf16 = 24 MB  [0,24)
    u16* vTb   = (u16*)(ws + 24 * MB);   // 512x4096        = 4 MB  [24,28)
    u16* xbf   = (u16*)(ws + 28 * MB);   // 4096x2048       = 16 MB [28,44) dead after QKV GEMM
    u16* ctx   = (u16*)(ws + 28 * MB);   // reuses xbf region
    u16* wqkvT = (u16*)(ws + 44 * MB);   // 3072x2048       = 12 MB [44,56) dead after QKV GEMM
    u16* woT   = (u16*)(ws + 44 * MB);   // reuses wqkvT region (8 MB)
    u16* qwb   = (u16*)(ws + 56 * MB);
    u16* kwb   = (u16*)(ws + 56 * MB + 256);

    convert_k<<<8192, 256, 0, stream>>>(x, xbf, 8388608L);
    convert_small_k<<<1, 128, 0, stream>>>(qw, kw, qwb, kwb);

    // fused weight: rows 0..2047 = Wq^T, 2048..2559 = Wk^T, 2560..3071 = Wv^T
    transpose_f32_k<<<dim3(32, 32), 256, 0, stream>>>(Wq, wqkvT, 2048, 2048);
    transpose_f32_k<<<dim3(8, 32), 256, 0, stream>>>(Wk, wqkvT + 2048L * 2048, 2048, 512);
    transpose_f32_k<<<dim3(8, 32), 256, 0, stream>>>(Wv, wqkvT + 2560L * 2048, 2048, 512);

    // QKV GEMM: (4096x2048) x (3072x2048)^T -> 4096x3072, 256^2 tiles, 128 KiB dynamic LDS
    gemm256<u16><<<dim3(12, 16), 512, 131072, stream>>>(xbf, wqkvT, qkvb, 3072, 2048);

    // v columns (2560..3071) -> vT (512, 4096)
    transpose_bf_k<<<dim3(8, 64), 256, 0, stream>>>(qkvb + 2560, 3072L, vTb, 4096, 512);

    normrope<<<16384, 256, 0, stream>>>(qkvb, 3072L, NHEADS, qwb, cosi, sini, 0.08838834764831845f);
    normrope<<<4096, 256, 0, stream>>>(qkvb + 2048, 3072L, NGRP, kwb, cosi, sini, 1.0f);

    // Wo^T into the (now dead) wqkvT region
    transpose_f32_k<<<dim3(32, 32), 256, 0, stream>>>(Wo, woT, 2048, 2048);

    attn<<<dim3(512, 1, 1), 256, 0, stream>>>(qkvb, vTb, ctx);

    // out GEMM: (4096x2048) x (2048x2048)^T -> 4096x2048 fp32
    gemm256<float><<<dim3(8, 16), 512, 131072, stream>>>(ctx, woT, out, 2048, 2048);
}

// Round 5
// 320.193 us; speedup vs baseline: 1.9896x; 1.1070x over previous
//
#include <hip/hip_runtime.h>
#include <cstdint>
#include <cstddef>

typedef unsigned short u16;
typedef __bf16 bf16x8 __attribute__((ext_vector_type(8)));
typedef float f32x4 __attribute__((ext_vector_type(4)));

#define SLEN 2048
#define NHEADS 16
#define NGRP 4

__device__ inline float bf2f(u16 u) { return __uint_as_float(((unsigned)u) << 16); }
__device__ inline u16 f2bf(float f) {
    unsigned u = __float_as_uint(f);
    u += 0x7fffu + ((u >> 16) & 1u);
    return (u16)(u >> 16);
}

__device__ inline f32x4 mfma16(bf16x8 a, bf16x8 b, f32x4 c) {
    return __builtin_amdgcn_mfma_f32_16x16x32_bf16(a, b, c, 0, 0, 0);
}

__device__ inline void memfence_compiler() { __asm__ volatile("" ::: "memory"); }

// async global->LDS, 16B per lane; LDS dest = wave-uniform base + lane*16
__device__ inline void cp16(const u16* g, u16* l) {
    __builtin_amdgcn_global_load_lds(
        (__attribute__((address_space(1))) void*)(u16*)g,
        (__attribute__((address_space(3))) void*)l, 16, 0, 0);
}

// ---------------- device bodies for fused prep/mid kernels ----------------

// fp32 (R,C) -> bf16 (C,R) transpose through LDS tile
__device__ inline void transpose_f32_body(u16 (*tile)[65], const float* __restrict__ in,
                                          u16* __restrict__ out, int R, int C, int bx, int by,
                                          int tid) {
    const long r0 = (long)by * 64, c0 = (long)bx * 64;
    for (int j = 0; j < 4; j++) {
        int c = j * 256 + tid;
        int lr = c >> 4, lc = (c & 15) * 4;
        float4 v = *(const float4*)&in[(r0 + lr) * (long)C + c0 + lc];
        tile[lr][lc + 0] = f2bf(v.x); tile[lr][lc + 1] = f2bf(v.y);
        tile[lr][lc + 2] = f2bf(v.z); tile[lr][lc + 3] = f2bf(v.w);
    }
    __syncthreads();
    for (int j = 0; j < 4; j++) {
        int c = j * 256 + tid;
        int orow = c >> 4, oc = (c & 15) * 4;
        ushort4 vv;
        vv.x = tile[oc + 0][orow]; vv.y = tile[oc + 1][orow];
        vv.z = tile[oc + 2][orow]; vv.w = tile[oc + 3][orow];
        *(ushort4*)&out[(c0 + orow) * (long)R + r0 + oc] = vv;
    }
}

// bf16 (R,C)@inRS -> bf16 (C,R) transpose through LDS tile
__device__ inline void transpose_bf_body(u16 (*tile)[65], const u16* __restrict__ in, long inRS,
                                         u16* __restrict__ out, int R, int C, int bx, int by,
                                         int tid) {
    const long r0 = (long)by * 64, c0 = (long)bx * 64;
    for (int j = 0; j < 4; j++) {
        int c = j * 256 + tid;
        int lr = c >> 4, lc = (c & 15) * 4;
        ushort4 vv = *(const ushort4*)&in[(r0 + lr) * inRS + c0 + lc];
        tile[lr][lc + 0] = vv.x; tile[lr][lc + 1] = vv.y;
        tile[lr][lc + 2] = vv.z; tile[lr][lc + 3] = vv.w;
    }
    __syncthreads();
    for (int j = 0; j < 4; j++) {
        int c = j * 256 + tid;
        int orow = c >> 4, oc = (c & 15) * 4;
        ushort4 vv;
        vv.x = tile[oc + 0][orow]; vv.y = tile[oc + 1][orow];
        vv.z = tile[oc + 2][orow]; vv.w = tile[oc + 3][orow];
        *(ushort4*)&out[(c0 + orow) * (long)R + r0 + oc] = vv;
    }
}

// RMSNorm + RoPE + scale, one wave per 128-elem head-row
__device__ inline void normrope_body(u16* __restrict__ buf, long rowstride, int heads,
                                     const u16* __restrict__ w,
                                     const float* __restrict__ cosf, const float* __restrict__ sinf,
                                     float scale, int row, int lane) {
    u16* p = buf + (long)(row / heads) * rowstride + (row % heads) * 128;
    float x1 = bf2f(p[lane]);
    float x2 = bf2f(p[lane + 64]);
    float ss = x1 * x1 + x2 * x2;
    for (int off = 1; off < 64; off <<= 1) ss += __shfl_xor(ss, off);
    float inv = rsqrtf(ss * (1.f / 128.f) + 1e-6f);
    int s = (row / heads) % SLEN;
    float c1 = cosf[s * 128 + lane], c2 = cosf[s * 128 + 64 + lane];
    float s1 = sinf[s * 128 + lane], s2 = sinf[s * 128 + 64 + lane];
    float w1 = bf2f(w[lane]), w2 = bf2f(w[lane + 64]);
    float y1 = x1 * inv * w1, y2 = x2 * inv * w2;
    p[lane]      = f2bf((y1 * c1 - y2 * s1) * scale);
    p[lane + 64] = f2bf((y2 * c2 + y1 * s2) * scale);
}

// ---------------- PREP: convert x + convert qw/kw + Wq/Wk/Wv transposes (1 launch) ----------
// blocks [0,8192): x fp32->bf16 | 8192: qw/kw | [8193,9217): Wq^T | [9217,9473): Wk^T
// [9473,9729): Wv^T. All pieces write disjoint buffers; no intra-kernel deps.
__global__ __launch_bounds__(256) void prep_k(const float* __restrict__ x, u16* __restrict__ xbf,
                                              const float* __restrict__ qw, const float* __restrict__ kw,
                                              u16* qwb, u16* kwb,
                                              const float* __restrict__ Wq, const float* __restrict__ Wk,
                                              const float* __restrict__ Wv, u16* __restrict__ wqkvT) {
    __shared__ u16 tile[64][65];
    const int bid = blockIdx.x, tid = threadIdx.x;
    if (bid < 8192) {
        long i = ((long)bid * 256 + tid) * 4;
        float4 v = *(const float4*)(x + i);
        ushort4 o;
        o.x = f2bf(v.x); o.y = f2bf(v.y); o.z = f2bf(v.z); o.w = f2bf(v.w);
        *(ushort4*)(xbf + i) = o;
    } else if (bid == 8192) {
        if (tid < 128) qwb[tid] = f2bf(qw[tid]);
        else kwb[tid - 128] = f2bf(kw[tid - 128]);
    } else if (bid < 9217) {
        int rem = bid - 8193;
        transpose_f32_body(tile, Wq, wqkvT, 2048, 2048, rem & 31, rem >> 5, tid);
    } else if (bid < 9473) {
        int rem = bid - 9217;
        transpose_f32_body(tile, Wk, wqkvT + 2048L * 2048, 2048, 512, rem & 7, rem >> 3, tid);
    } else {
        int rem = bid - 9473;
        transpose_f32_body(tile, Wv, wqkvT + 2560L * 2048, 2048, 512, rem & 7, rem >> 3, tid);
    }
}

// ---------------- MID: vT transpose + normrope(q) + normrope(k) + Wo^T (1 launch) ----------
// blocks [0,512): v cols -> vT | [512,16896): normrope q | [16896,20992): normrope k
// [20992,22016): Wo^T into dead wqkvT region. Disjoint regions; no intra-kernel deps.
__global__ __launch_bounds__(256) void mid_k(u16* __restrict__ qkvb, u16* __restrict__ vTb,
                                             const u16* __restrict__ qwb, const u16* __restrict__ kwb,
                                             const float* __restrict__ cosf, const float* __restrict__ sinf,
                                             const float* __restrict__ Wo, u16* __restrict__ woT) {
    __shared__ u16 tile[64][65];
    const int bid = blockIdx.x, tid = threadIdx.x;
    if (bid < 512) {
        transpose_bf_body(tile, qkvb + 2560, 3072L, vTb, 4096, 512, bid & 7, bid >> 3, tid);
    } else if (bid < 16896) {
        int row = (bid - 512) * 4 + (tid >> 6);
        normrope_body(qkvb, 3072L, NHEADS, qwb, cosf, sinf, 0.08838834764831845f, row, tid & 63);
    } else if (bid < 20992) {
        int row = (bid - 16896) * 4 + (tid >> 6);
        normrope_body(qkvb + 2048, 3072L, NGRP, kwb, cosf, sinf, 1.0f, row, tid & 63);
    } else {
        int rem = bid - 20992;
        transpose_f32_body(tile, Wo, woT, 2048, 2048, rem & 31, rem >> 5, tid);
    }
}

// ---------------- GEMM: BM=MQ*128 x 256 tile, BK=64, counted-vmcnt double buffer ----------
// C(M,N) = A(M,K)*Bt(N,K)^T, bf16 in, OutT out. 512 threads = 8 waves ((MQ)M x 4N),
// per-wave C = MQ*64 x 64. LDS: [As0|As1|Bs0|Bs1], A tile = BM*64, B tile = 256*64 u16.
// While computing tile t from buf[t&1], tile t+1's loads fly into buf[~t&1]; wait is
// counted vmcnt(2*MQ+4) (tile t's own loads landed, t+1's stay in flight) + raw s_barrier.
// T2 swizzle both-sides (rule 21): linear LDS dest; SOURCE chunk c^(r&7); READ chunk
// (ks*4+quad)^(row&7).
template <typename OutT, int MQ>
__global__ __launch_bounds__(512, 2) void gemm256(const u16* __restrict__ A, const u16* __restrict__ Bt,
                                                  OutT* __restrict__ C, int N, int K) {
    extern __shared__ u16 smem[];
    const int tid = threadIdx.x;
    const int lane = tid & 63, wave = tid >> 6;
    const int l15 = lane & 15, quad = lane >> 4;
    const int wm = (wave >> 2) * (MQ * 64), wn = (wave & 3) * 64;
    const long m0 = (long)blockIdx.y * (MQ * 128), n0 = (long)blockIdx.x * 256;

    constexpr int ASZ = MQ * 8192;          // u16 per A tile (BM*64)

    f32x4 acc[MQ * 4][4];
    #pragma unroll
    for (int i = 0; i < MQ * 4; i++)
        #pragma unroll
        for (int j = 0; j < 4; j++) acc[i][j] = {0.f, 0.f, 0.f, 0.f};

    const int sn = wave * 64 + lane;        // 0..511
    const u16* aBase = A + m0 * (long)K;
    const u16* bBase = Bt + n0 * (long)K;

    auto stage = [&](int kt, int p) {
        u16* al = smem + p * ASZ + wave * 512;
        u16* bl = smem + 2 * ASZ + p * 16384 + wave * 512;
        #pragma unroll
        for (int j = 0; j < MQ * 2; j++) {
            int n = j * 512 + sn;
            int r = n >> 3;
            int c = (n & 7) ^ (r & 7);
            cp16(aBase + (long)r * K + kt + c * 8, al + j * 4096);
        }
        #pragma unroll
        for (int j = 0; j < 4; j++) {
            int n = j * 512 + sn;
            int r = n >> 3;
            int c = (n & 7) ^ (r & 7);
            cp16(bBase + (long)r * K + kt + c * 8, bl + j * 4096);
        }
    };

    stage(0, 0);
    const int nkt = K >> 6;

    for (int t = 0; t < nkt; ++t) {
        const int cur = t & 1;
        if (t + 1 < nkt) {
            stage((t + 1) << 6, cur ^ 1);
            if constexpr (MQ == 2) asm volatile("s_waitcnt vmcnt(8)" ::: "memory");
            else                   asm volatile("s_waitcnt vmcnt(6)" ::: "memory");
        } else {
            asm volatile("s_waitcnt vmcnt(0)" ::: "memory");
        }
        __builtin_amdgcn_s_barrier();

        const u16* asb = smem + cur * ASZ;
        const u16* bsb = smem + 2 * ASZ + cur * 16384;

        bf16x8 bfr[4][2];
        #pragma unroll
        for (int ni = 0; ni < 4; ni++) {
            const int row = wn + ni * 16 + l15;
            #pragma unroll
            for (int ks = 0; ks < 2; ks++)
                bfr[ni][ks] = *(const bf16x8*)&bsb[row * 64 + (((ks << 2) + quad) ^ (row & 7)) * 8];
        }
        #pragma unroll
        for (int mq = 0; mq < MQ; mq++) {
            bf16x8 af[4][2];
            #pragma unroll
            for (int mi = 0; mi < 4; mi++) {
                const int row = wm + mq * 64 + mi * 16 + l15;
                #pragma unroll
                for (int ks = 0; ks < 2; ks++)
                    af[mi][ks] = *(const bf16x8*)&asb[row * 64 + (((ks << 2) + quad) ^ (row & 7)) * 8];
            }
            #pragma unroll
            for (int mi = 0; mi < 4; mi++)
                #pragma unroll
                for (int ni = 0; ni < 4; ni++) {
                    f32x4 v = acc[mq * 4 + mi][ni];
                    v = mfma16(af[mi][0], bfr[ni][0], v);
                    v = mfma16(af[mi][1], bfr[ni][1], v);
                    acc[mq * 4 + mi][ni] = v;
                }
        }
        __builtin_amdgcn_s_barrier();
    }

    #pragma unroll
    for (int mi = 0; mi < MQ * 4; mi++)
        #pragma unroll
        for (int r = 0; r < 4; r++) {
            long row = m0 + wm + mi * 16 + quad * 4 + r;
            OutT* crow = C + row * (long)N + n0 + wn + l15;
            #pragma unroll
            for (int ni = 0; ni < 4; ni++) {
                float v = acc[mi][ni][r];
                if constexpr (sizeof(OutT) == 2) crow[ni * 16] = f2bf(v);
                else crow[ni * 16] = v;
            }
        }
}

// ---------------- causal flash attention v5: block-shared LDS K/V staging ----------------
// (unchanged: 80.2 us, MfmaUtil 18%)
__global__ __launch_bounds__(256, 2) void attn(const u16* __restrict__ qkv, const u16* __restrict__ vT,
                                               u16* __restrict__ ctx) {
    __shared__ u16 KB[64 * 128];       // K tile: row t (64) x col d (128), swizzled
    __shared__ u16 VB[128 * 64];       // V tile: row d (128) x col t (64), swizzled
    __shared__ u16 Ps[4][2][16][72];   // [wave][m][qrow16][t+pad]
    __shared__ float Al[4][2][16];     // alpha axis-swap
    const int tid = threadIdx.x;
    const int lane = tid & 63, wave = tid >> 6;
    const int l15 = lane & 15, quad = lane >> 4;
    const int bg = blockIdx.x & 7, b = bg >> 2, g = bg & 3;
    const int rest = blockIdx.x >> 3;
    const int h = g * 4 + (rest & 3);
    const int idx = rest >> 2;
    const int qt = (idx < 8) ? (15 - idx) : (idx - 8);   // complementary pairing
    const int wr = qt * 128 + wave * 32;    // this wave's first q-row

    union { bf16x8 v; u16 s[8]; } uo;
    for (int j = 0; j < 8; j++) uo.s[j] = 0x3F80;  // bf16 1.0
    const bf16x8 ones = uo.v;

    // Q fragments (B-operand layout; identical register layout to A)
    bf16x8 qa[2][4];
    for (int m = 0; m < 2; m++) {
        const u16* qp = qkv + (long)(b * SLEN + wr + m * 16 + l15) * 3072 + h * 128 + quad * 8;
        for (int kc = 0; kc < 4; kc++) qa[m][kc] = *(const bf16x8*)(qp + kc * 32);
    }
    float m_i[2] = {-__builtin_inff(), -__builtin_inff()};  // per q-row (m*16+l15)
    f32x4 l_acc[2];
    f32x4 o[2][8];
    for (int m = 0; m < 2; m++) l_acc[m] = {0.f, 0.f, 0.f, 0.f};
    for (int m = 0; m < 2; m++)
        for (int nf = 0; nf < 8; nf++) o[m][nf] = {0.f, 0.f, 0.f, 0.f};

    const u16* kqb = qkv + (long)b * SLEN * 3072 + 2048 + g * 128;   // K cols of (b,g)
    const u16* vgb = vT + (long)g * 128 * 4096 + (long)b * SLEN;     // vT rows of (b,g)
    const int xk = (l15 & 7) << 4;     // read-side swizzle XOR (byte)
    const int nt = 2 * qt + 2;         // block-uniform tile count

    for (int t = 0; t < nt; ++t) {
        const int t0 = t * 64;
        // ---- stage K (16 KB) + V (16 KB) into LDS; linear dest, pre-swizzled source ----
        #pragma unroll
        for (int i = 0; i < 4; ++i) {
            const int j = wave * 4 + i;
            {   // K: instr j covers rows j*4 .. j*4+3 (256 B/row, 16 chunks)
                const int row = j * 4 + (lane >> 4);
                const int cs = lane & 15;
                cp16(kqb + (long)(t0 + row) * 3072 + ((cs ^ (row & 7)) * 8), &KB[j * 512]);
            }
            {   // V: instr j covers rows j*8 .. j*8+7 (128 B/row, 8 chunks)
                const int row = j * 8 + (lane >> 3);
                const int cs = lane & 7;
                cp16(vgb + (long)row * 4096 + t0 + ((cs ^ (row & 7)) * 8), &VB[j * 512]);
            }
        }
        __syncthreads();   // drains each wave's vmcnt, then barrier: staging visible

        if (t0 <= wr + 31) {
            // K fragments from LDS (swizzled read)
            bf16x8 kf[4][4];
            #pragma unroll
            for (int nf = 0; nf < 4; nf++)
                #pragma unroll
                for (int kc = 0; kc < 4; kc++)
                    kf[nf][kc] = *(const bf16x8*)((const char*)KB +
                                  (nf * 16 + l15) * 256 + ((quad * 16 + kc * 64) ^ xk));

            // S^T = K * Q^T
            f32x4 sc[2][4];
            for (int m = 0; m < 2; m++)
                for (int nf = 0; nf < 4; nf++) sc[m][nf] = {0.f, 0.f, 0.f, 0.f};
            #pragma unroll
            for (int kc = 0; kc < 4; kc++)
                #pragma unroll
                for (int nf = 0; nf < 4; nf++) {
                    sc[0][nf] = mfma16(kf[nf][kc], qa[0][kc], sc[0][nf]);
                    sc[1][nf] = mfma16(kf[nf][kc], qa[1][kc], sc[1][nf]);
                }
            // causal mask: t = t0+nf*16+quad*4+r (rows), qrow = wr+m*16+l15 (cols)
            if (t0 + 63 > wr) {
                #pragma unroll
                for (int m = 0; m < 2; m++) {
                    int qrow = wr + m * 16 + l15;
                    #pragma unroll
                    for (int nf = 0; nf < 4; nf++)
                        #pragma unroll
                        for (int r = 0; r < 4; r++)
                            if (t0 + nf * 16 + quad * 4 + r > qrow) sc[m][nf][r] = -__builtin_inff();
                }
            }
            // row max: in-lane over nf,r then across quads (2 shuffles)
            float alpha[2];
            #pragma unroll
            for (int m = 0; m < 2; m++) {
                float mx = sc[m][0][0];
                #pragma unroll
                for (int nf = 0; nf < 4; nf++)
                    #pragma unroll
                    for (int r = 0; r < 4; r++) mx = fmaxf(mx, sc[m][nf][r]);
                mx = fmaxf(mx, __shfl_xor(mx, 16));
                mx = fmaxf(mx, __shfl_xor(mx, 32));
                float mn = fmaxf(m_i[m], mx);
                alpha[m] = __expf(m_i[m] - mn);
                m_i[m] = mn;
                Al[wave][m][l15] = alpha[m];
            }
            // exp + P store (P^T C-layout -> A-layout rows: 4 consecutive t per lane = b64)
            #pragma unroll
            for (int m = 0; m < 2; m++)
                #pragma unroll
                for (int nf = 0; nf < 4; nf++) {
                    ushort4 pk;
                    pk.x = f2bf(__expf(sc[m][nf][0] - m_i[m]));
                    pk.y = f2bf(__expf(sc[m][nf][1] - m_i[m]));
                    pk.z = f2bf(__expf(sc[m][nf][2] - m_i[m]));
                    pk.w = f2bf(__expf(sc[m][nf][3] - m_i[m]));
                    *(ushort4*)&Ps[wave][m][l15][nf * 16 + quad * 4] = pk;
                }
            memfence_compiler();
            // alpha on O-row axis (broadcast read), rescale o and l
            f32x4 al[2];
            al[0] = *(const f32x4*)&Al[wave][0][quad * 4];
            al[1] = *(const f32x4*)&Al[wave][1][quad * 4];
            #pragma unroll
            for (int m = 0; m < 2; m++) {
                #pragma unroll
                for (int nf = 0; nf < 8; nf++)
                    #pragma unroll
                    for (int r = 0; r < 4; r++) o[m][nf][r] *= al[m][r];
                #pragma unroll
                for (int r = 0; r < 4; r++) l_acc[m][r] *= al[m][r];
            }
            // PV, half 0 (V fragments from LDS, swizzled read)
            {
                bf16x8 vf[8];
                #pragma unroll
                for (int nf = 0; nf < 8; nf++)
                    vf[nf] = *(const bf16x8*)((const char*)VB +
                              (nf * 16 + l15) * 128 + ((quad * 16) ^ xk));
                bf16x8 pa0 = *(const bf16x8*)&Ps[wave][0][l15][quad * 8];
                bf16x8 pa1 = *(const bf16x8*)&Ps[wave][1][l15][quad * 8];
                #pragma unroll
                for (int nf = 0; nf < 8; nf++) {
                    o[0][nf] = mfma16(pa0, vf[nf], o[0][nf]);
                    o[1][nf] = mfma16(pa1, vf[nf], o[1][nf]);
                }
                l_acc[0] = mfma16(pa0, ones, l_acc[0]);
                l_acc[1] = mfma16(pa1, ones, l_acc[1]);
            }
            // PV, half 1
            {
                bf16x8 vf[8];
                #pragma unroll
                for (int nf = 0; nf < 8; nf++)
                    vf[nf] = *(const bf16x8*)((const char*)VB +
                              (nf * 16 + l15) * 128 + ((64 + quad * 16) ^ xk));
                bf16x8 pa0 = *(const bf16x8*)&Ps[wave][0][l15][32 + quad * 8];
                bf16x8 pa1 = *(const bf16x8*)&Ps[wave][1][l15][32 + quad * 8];
                #pragma unroll
                for (int nf = 0; nf < 8; nf++) {
                    o[0][nf] = mfma16(pa0, vf[nf], o[0][nf]);
                    o[1][nf] = mfma16(pa1, vf[nf], o[1][nf]);
                }
                l_acc[0] = mfma16(pa0, ones, l_acc[0]);
                l_acc[1] = mfma16(pa1, ones, l_acc[1]);
            }
            memfence_compiler();
        }
        __syncthreads();   // all reads of KB/VB done before next tile's overwrite
    }

    #pragma unroll
    for (int m = 0; m < 2; m++)
        #pragma unroll
        for (int r = 0; r < 4; r++) {
            float inv = 1.f / l_acc[m][r];
            int srow = wr + m * 16 + quad * 4 + r;
            u16* cp = ctx + (long)(b * SLEN + srow) * 2048 + h * 128 + l15;
            #pragma unroll
            for (int nf = 0; nf < 8; nf++) cp[nf * 16] = f2bf(o[m][nf][r] * inv);
        }
}

extern "C" void kernel_launch(void* const* d_in, const int* in_sizes, int n_in,
                              void* d_out, int out_size, void* d_ws, size_t ws_size,
                              hipStream_t stream) {
    const float* x    = (const float*)d_in[0];
    // d_in[1] = mask (unused; causality from indices)
    const float* cosi = (const float*)d_in[2];
    const float* sini = (const float*)d_in[3];
    const float* Wq   = (const float*)d_in[4];
    const float* Wk   = (const float*)d_in[5];
    const float* Wv   = (const float*)d_in[6];
    const float* Wo   = (const float*)d_in[7];
    const float* qw   = (const float*)d_in[8];
    const float* kw   = (const float*)d_in[9];
    float* out = (float*)d_out;
    char* ws = (char*)d_ws;

    const size_t MB = 1 << 20;
    u16* qkvb  = (u16*)(ws);             // 4096x3072 bf16 = 24 MB  [0,24)
    u16* vTb   = (u16*)(ws + 24 * MB);   // 512x4096        = 4 MB  [24,28)
    u16* xbf   = (u16*)(ws + 28 * MB);   // 4096x2048       = 16 MB [28,44) dead after QKV GEMM
    u16* ctx   = (u16*)(ws + 28 * MB);   // reuses xbf region
    u16* wqkvT = (u16*)(ws + 44 * MB);   // 3072x2048       = 12 MB [44,56) dead after QKV GEMM
    u16* woT   = (u16*)(ws + 44 * MB);   // reuses wqkvT region (8 MB)
    u16* qwb   = (u16*)(ws + 56 * MB);
    u16* kwb   = (u16*)(ws + 56 * MB + 256);

    // 1) prep: convert x, convert qw/kw, transpose Wq/Wk/Wv into fused wqkvT
    prep_k<<<9729, 256, 0, stream>>>(x, xbf, qw, kw, qwb, kwb, Wq, Wk, Wv, wqkvT);

    // 2) QKV GEMM: (4096x2048) x (3072x2048)^T -> 4096x3072 bf16
    gemm256<u16, 2><<<dim3(12, 16), 512, 131072, stream>>>(xbf, wqkvT, qkvb, 3072, 2048);

    // 3) mid: vT transpose, normrope q, normrope k, Wo^T (into dead wqkvT region)
    mid_k<<<22016, 256, 0, stream>>>(qkvb, vTb, qwb, kwb, cosi, sini, Wo, woT);

    // 4) attention
    attn<<<dim3(512, 1, 1), 256, 0, stream>>>(qkvb, vTb, ctx);

    // 5) out GEMM: BM=128 -> 256 blocks (full CU util): (4096x2048) x (2048x2048)^T fp32
    gemm256<float, 1><<<dim3(8, 32), 512, 98304, stream>>>(ctx, woT, out, 2048, 2048);
}